// Round 2
// baseline (679.097 us; speedup 1.0000x reference)
//
#include <hip/hip_runtime.h>
#include <hip/hip_bf16.h>
#include <math.h>

#define H 64
#define DM 128
#define GDIM 192      // 3*H
#define BSZ 32
#define SEQ 500
#define NROW (BSZ*SEQ)  // 16000
#define LIBN 2145
#define FFD 128
#define KPAD 2176     // 68*32 (theta K padded)
#define NKC 68        // K chunks of 32

typedef __attribute__((ext_vector_type(8))) short short8;   // bf16x8 MFMA operand
typedef __attribute__((ext_vector_type(4))) float f32x4;    // MFMA accumulator
typedef __attribute__((ext_vector_type(4))) unsigned u32x4;

__device__ __forceinline__ float sigf(float x) {
    return 1.0f / (1.0f + __expf(-x));
}
__device__ __forceinline__ float tanhfast(float x) {
    x = fminf(fmaxf(x, -15.0f), 15.0f);
    float t = __expf(-2.0f * x);
    return (1.0f - t) / (1.0f + t);
}
__device__ __forceinline__ short bf16r(float f) {   // fp32 -> bf16 rne
    unsigned u = __float_as_uint(f);
    unsigned r = (u + 0x7fffu + ((u >> 16) & 1u)) >> 16;
    return (short)r;
}

// raw barrier: LDS ordering only — xp prefetch loads / h1 stores stay in flight.
#define BAR_LGKM() asm volatile("s_waitcnt lgkmcnt(0)\n\ts_barrier" ::: "memory")

// ---------------- pack Wih0 (192,128) -> WTp[k4][g][e] for coalesced float4 loads ----
__global__ void pack_wih0(const float* __restrict__ w, float* __restrict__ wt) {
    int idx = blockIdx.x * 256 + threadIdx.x;
    if (idx >= GDIM * DM) return;
    int e  = idx & 3;
    int g  = (idx >> 2) % GDIM;
    int k4 = idx / (GDIM * 4);
    wt[idx] = w[g * DM + k4 * 4 + e];
}

// ---- prepack coef (2145x64, zero-pad to 2176) into bf16 B-fragment-linear order ----
__global__ void pack_coef_frag(const float* __restrict__ coef, short* __restrict__ cp) {
    int idx = blockIdx.x * 256 + threadIdx.x;           // 68*4*64*8 = 139264
    int j = idx & 7, lane = (idx >> 3) & 63, nt = (idx >> 9) & 3, kc = idx >> 11;
    int k = kc * 32 + ((lane >> 4) << 3) + j;
    int c = nt * 16 + (lane & 15);
    float v = (k < LIBN) ? coef[(size_t)k * H + c] : 0.0f;
    cp[idx] = bf16r(v);
}
// ---- W1 (128,64): B = W1^T (K=64,N=128) ----
__global__ void pack_w1_frag(const float* __restrict__ w1, short* __restrict__ wp) {
    int idx = blockIdx.x * 256 + threadIdx.x;           // 2*8*64*8 = 8192
    int j = idx & 7, lane = (idx >> 3) & 63, nt = (idx >> 9) & 7, kc = idx >> 12;
    int k = kc * 32 + ((lane >> 4) << 3) + j;
    int n = nt * 16 + (lane & 15);
    wp[idx] = bf16r(w1[(size_t)n * H + k]);
}
// ---- W2 (64,128): B = W2^T (K=128,N=64) ----
__global__ void pack_w2_frag(const float* __restrict__ w2, short* __restrict__ wp) {
    int idx = blockIdx.x * 256 + threadIdx.x;           // 4*4*64*8 = 8192
    int j = idx & 7, lane = (idx >> 3) & 63, nt = (idx >> 9) & 3, kc = idx >> 11;
    int k = kc * 32 + ((lane >> 4) << 3) + j;
    int n = nt * 16 + (lane & 15);
    wp[idx] = bf16r(w2[(size_t)n * FFD + k]);
}

// ---------------- xp0 = x @ Wih0^T + bih0, stored in GRU chunk layout ----------------
__global__ __launch_bounds__(192, 2) void xp0_gemm(const float* __restrict__ x,
                                                   const float* __restrict__ wtp,
                                                   const float* __restrict__ bih0,
                                                   float* __restrict__ xpT) {
    __shared__ float xs[64][DM];
    int rb = blockIdx.x * 64;
    for (int idx = threadIdx.x; idx < 64 * 32; idx += 192) {
        int r = idx >> 5, k4 = idx & 31;
        ((f32x4*)xs[r])[k4] = ((const f32x4*)(x + (size_t)(rb + r) * DM))[k4];
    }
    __syncthreads();
    int g = threadIdx.x;
    float bias = bih0[g];
    float acc[64];
#pragma unroll
    for (int r = 0; r < 64; r++) acc[r] = bias;
    for (int k4 = 0; k4 < 32; k4++) {
        f32x4 w4 = ((const f32x4*)wtp)[k4 * GDIM + g];
#pragma unroll
        for (int r = 0; r < 64; r++) {
            f32x4 xv = ((f32x4*)xs[r])[k4];
            acc[r] += w4[0] * xv[0] + w4[1] * xv[1] + w4[2] * xv[2] + w4[3] * xv[3];
        }
    }
    for (int r = 0; r < 64; r++) {
        int row = rb + r;
        int bb = row / 500;
        int ss = row - bb * 500;
        xpT[(((size_t)bb * 125 + (ss >> 2)) * GDIM + g) * 4 + (ss & 3)] = acc[r];
    }
}

// ---------------- fused 2-layer GRU scan: 3-wave / 1-barrier structure ---------------
// One wave per matvec, full K=64 per wave, weights register-resident (192 VGPR):
//   wave0: Whh0@h0  -> computes h0[u]   = GRU(h0[u-1], xp[u]) entirely in-lane
//   wave1: Wih1@h0  -> computes i1 = Wih1@h0[u-1] + bih1, hands f32x4 to wave2 via LDS
//   wave2: Whh1@h1  -> computes h1[u-2] = GRU(h1[u-3], i1(h0[u-2])) entirely in-lane
// Lane i owns gate rows {i, 64+i, 128+i}: r/z/n land in the lane that needs them ->
// NO cross-wave reduction, ONE barrier/step, 3-wave rendezvous (was 12 waves, 2 bars).
// h broadcast is a wave-uniform LDS read (free). h0 / p1 double-buffered by parity.
// Skew: u = 0..501; layer0 at u, Wih1 at u (for h0[u-1]), layer1 at u (for h1[u-2]).
__global__ __launch_bounds__(192, 1) void gru_fused(const float* __restrict__ xpT,
                                                    const float* __restrict__ whh0,
                                                    const float* __restrict__ bhh0,
                                                    const float* __restrict__ wih1,
                                                    const float* __restrict__ bih1,
                                                    const float* __restrict__ whh1,
                                                    const float* __restrict__ bhh1,
                                                    float* __restrict__ hbuf) {
    int b = blockIdx.x;
    int tid = threadIdx.x;
    int wv = __builtin_amdgcn_readfirstlane(tid >> 6);
    int lane = tid & 63;

    __shared__ __align__(16) float h0s[2][H];      // parity-buffered h0
    __shared__ __align__(16) float h1bc[H];        // wave2's own h1 broadcast
    __shared__ __align__(16) float p1s[2][H][4];   // wave1 -> wave2 handoff {r,z,n,_}

    if (tid < H) { h0s[1][tid] = 0.0f; h1bc[tid] = 0.0f; }

    const float* W  = (wv == 0) ? whh0 : (wv == 1) ? wih1 : whh1;
    const float* Bv = (wv == 0) ? bhh0 : (wv == 1) ? bih1 : bhh1;
    f32x4 wrv[16], wzv[16], wnv[16];               // 192 VGPRs of weights
#pragma unroll
    for (int t = 0; t < 16; t++) {
        wrv[t] = ((const f32x4*)(W + (size_t)lane * H))[t];
        wzv[t] = ((const f32x4*)(W + (size_t)(H + lane) * H))[t];
        wnv[t] = ((const f32x4*)(W + (size_t)(2 * H + lane) * H))[t];
    }
    float br = Bv[lane], bz = Bv[H + lane], bn = Bv[2 * H + lane];

    float hreg0 = 0.0f, hreg1 = 0.0f;
    float hb4[4] = {0.f, 0.f, 0.f, 0.f};
    f32x4 xc[4][3];
    const float* xpB = xpT + (size_t)b * 125 * GDIM * 4;

    if (wv == 0) {
#pragma unroll
        for (int g3 = 0; g3 < 3; g3++) {
            xc[0][g3] = *(const f32x4*)(xpB + ((size_t)0 * GDIM + g3 * 64 + lane) * 4);
            xc[1][g3] = *(const f32x4*)(xpB + ((size_t)1 * GDIM + g3 * 64 + lane) * 4);
        }
    }
    __syncthreads();

    auto loadch = [&](int c, int buf) {
        if (c < 125) {
#pragma unroll
            for (int g3 = 0; g3 < 3; g3++)
                xc[buf][g3] = *(const f32x4*)(xpB + ((size_t)c * GDIM + g3 * 64 + lane) * 4);
        }
    };

    // full-K matvec: 16 wave-uniform b128 LDS reads + 192 FMAs (3 indep acc chains)
    auto matvec = [&](const float* hb, float& gr, float& gz, float& gn) {
        f32x4 hv[16];
#pragma unroll
        for (int t = 0; t < 16; t++) hv[t] = ((const f32x4*)hb)[t];
        float ar = br, az = bz, an = bn;
#pragma unroll
        for (int t = 0; t < 16; t++) {
            ar += wrv[t][0] * hv[t][0] + wrv[t][1] * hv[t][1]
                + wrv[t][2] * hv[t][2] + wrv[t][3] * hv[t][3];
            az += wzv[t][0] * hv[t][0] + wzv[t][1] * hv[t][1]
                + wzv[t][2] * hv[t][2] + wzv[t][3] * hv[t][3];
            an += wnv[t][0] * hv[t][0] + wnv[t][1] * hv[t][1]
                + wnv[t][2] * hv[t][2] + wnv[t][3] * hv[t][3];
        }
        gr = ar; gz = az; gn = an;
    };

    // e = u&3 (compile-time at each call site); parities fold to constants.
    auto step = [&](int u, int e, float xr, float xz, float xn) {
        BAR_LGKM();   // one barrier per step: makes prior step's h0/p1 writes visible
        if (wv == 0) {
            if (u < SEQ) {
                float gr, gz, gn;
                matvec(h0s[(e + 1) & 1], gr, gz, gn);          // h0[u-1]
                float rg = sigf(xr + gr);
                float zg = sigf(xz + gz);
                float ng = tanhfast(xn + rg * gn);
                hreg0 = (1.0f - zg) * ng + zg * hreg0;
                h0s[e & 1][lane] = hreg0;                      // h0[u]
            }
        } else if (wv == 1) {
            if (u >= 1 && u <= 500) {
                float ar, az, an;
                matvec(h0s[(e + 1) & 1], ar, az, an);          // Wih1 @ h0[u-1] + bih1
                *(f32x4*)&p1s[(e + 1) & 1][lane][0] = (f32x4){ar, az, an, 0.0f};
            }
        } else {
            if (u >= 2) {
                float gr, gz, gn;
                matvec(h1bc, gr, gz, gn);                      // Whh1 @ h1[u-3] + bhh1
                f32x4 pv = *(const f32x4*)&p1s[e & 1][lane][0];// i1(h0[u-2])
                float rg = sigf(pv[0] + gr);
                float zg = sigf(pv[1] + gz);
                float ng = tanhfast(pv[2] + rg * gn);
                hreg1 = (1.0f - zg) * ng + zg * hreg1;         // h1[u-2]
                h1bc[lane] = hreg1;
                hb4[(e + 2) & 3] = hreg1;                      // t=u-2, t&3=(e+2)&3
                if (e == 1) {                                  // t&3==3: flush h1[u-5..u-2]
                    float* dst = hbuf + ((size_t)b * SEQ + (u - 5)) * H + lane;
#pragma unroll
                    for (int t = 0; t < 4; t++) dst[t * H] = hb4[t];
                }
            }
        }
    };

    for (int scb = 0; scb < 31; scb++) {
#pragma unroll
        for (int sci = 0; sci < 4; sci++) {
            int sc = scb * 4 + sci;
            if (wv == 0 && (sci & 1) == 0) {
                loadch(sc + 2, (sci + 2) & 3);
                loadch(sc + 3, (sci + 3) & 3);
            }
            int s0 = sc * 4;
            step(s0 + 0, 0, xc[sci][0][0], xc[sci][1][0], xc[sci][2][0]);
            step(s0 + 1, 1, xc[sci][0][1], xc[sci][1][1], xc[sci][2][1]);
            step(s0 + 2, 2, xc[sci][0][2], xc[sci][1][2], xc[sci][2][2]);
            step(s0 + 3, 3, xc[sci][0][3], xc[sci][1][3], xc[sci][2][3]);
        }
    }
    {   // sc = 124 (buf 0, loaded at sc=122): steps 496..499
        step(496, 0, xc[0][0][0], xc[0][1][0], xc[0][2][0]);
        step(497, 1, xc[0][0][1], xc[0][1][1], xc[0][2][1]);
        step(498, 2, xc[0][0][2], xc[0][1][2], xc[0][2][2]);
        step(499, 3, xc[0][0][3], xc[0][1][3], xc[0][2][3]);
    }
    // tail u = 500, 501: drain the skewed pipeline (wave1 at 500, wave2 at 500/501)
    step(500, 0, 0.0f, 0.0f, 0.0f);
    step(501, 1, 0.0f, 0.0f, 0.0f);
}

// ---------------- MFMA SINDy layer (unchanged) ---------------------------------------
__global__ __launch_bounds__(512) void sindy_mfma(float* __restrict__ hbuf,
                                                  const short* __restrict__ cpk,
                                                  const short* __restrict__ w1p,
                                                  const short* __restrict__ w2p,
                                                  const float* __restrict__ g1,
                                                  const float* __restrict__ b1n,
                                                  const float* __restrict__ bf1,
                                                  const float* __restrict__ bf2v,
                                                  const float* __restrict__ g2,
                                                  const float* __restrict__ b2n,
                                                  float* __restrict__ out,
                                                  int final_layer) {
    __shared__ float z[64 * 68];
    __shared__ float upd[64 * 68];
    __shared__ float ff[64 * 132];
    __shared__ unsigned kmap[KPAD];
    __shared__ float bfs1[FFD], bfs2[H], g1s[H], b1s[H], g2s[H], b2s[H];

    int tid = threadIdx.x;
    int wv = __builtin_amdgcn_readfirstlane(tid >> 6);
    int lane = tid & 63;
    int row0 = blockIdx.x * 64;

    for (int idx = tid; idx < 64 * 16; idx += 512) {
        int r = idx >> 4, c4 = idx & 15;
        *(f32x4*)&z[r * 68 + c4 * 4] = *(const f32x4*)&hbuf[(size_t)(row0 + r) * H + c4 * 4];
    }
    for (int idx = tid; idx < 64 * 17; idx += 512)
        *(f32x4*)&upd[idx * 4] = (f32x4){0.f, 0.f, 0.f, 0.f};
    if (tid < 64) {
        z[tid * 68 + 64] = 1.0f; z[tid * 68 + 65] = 0.0f;
        z[tid * 68 + 66] = 0.0f; z[tid * 68 + 67] = 0.0f;
    }
    for (int k = tid; k < KPAD; k += 512) {
        unsigned a, b;
        if (k == 0) { a = 64; b = 64; }
        else if (k < 1 + H) { a = (unsigned)(k - 1); b = 64; }
        else if (k < LIBN) {
            int qq = k - (1 + H);
            double s = sqrt(16641.0 - 8.0 * (double)qq);
            int i = (int)((129.0 - s) * 0.5);
            int base = 64 * i - (i * (i - 1)) / 2;
            a = (unsigned)i; b = (unsigned)(i + (qq - base));
        } else { a = 65; b = 65; }
        kmap[k] = (a << 16) | b;
    }
    if (tid < FFD) bfs1[tid] = bf1[tid];
    if (tid < H) {
        bfs2[tid] = bf2v[tid];
        g1s[tid] = g1[tid]; b1s[tid] = b1n[tid];
        g2s[tid] = g2[tid]; b2s[tid] = b2n[tid];
    }
    __syncthreads();

    int kj0 = ((lane >> 4) << 3);
    int m0 = (wv & 3) * 16;
    int m = m0 + (lane & 15);
    int rbase = m0 + ((lane >> 4) << 2);
    int cb16 = lane & 15;
    const float* zrow = &z[m * 68];

    // ---- phase 1: upd = theta @ coef (k-split 2-way) ----
    {
        int p = wv >> 2;
        f32x4 acc[4] = {{0,0,0,0},{0,0,0,0},{0,0,0,0},{0,0,0,0}};
        for (int kc = p; kc < NKC; kc += 2) {
            int kbase = kc * 32 + kj0;
            u32x4 km0 = *(const u32x4*)&kmap[kbase];
            u32x4 km1 = *(const u32x4*)&kmap[kbase + 4];
            short8 af;
            af[0] = bf16r(zrow[km0[0] >> 16] * zrow[km0[0] & 0xffff]);
            af[1] = bf16r(zrow[km0[1] >> 16] * zrow[km0[1] & 0xffff]);
            af[2] = bf16r(zrow[km0[2] >> 16] * zrow[km0[2] & 0xffff]);
            af[3] = bf16r(zrow[km0[3] >> 16] * zrow[km0[3] & 0xffff]);
            af[4] = bf16r(zrow[km1[0] >> 16] * zrow[km1[0] & 0xffff]);
            af[5] = bf16r(zrow[km1[1] >> 16] * zrow[km1[1] & 0xffff]);
            af[6] = bf16r(zrow[km1[2] >> 16] * zrow[km1[2] & 0xffff]);
            af[7] = bf16r(zrow[km1[3] >> 16] * zrow[km1[3] & 0xffff]);
            const short* cb = cpk + ((size_t)(kc * 4) * 64 + lane) * 8;
#pragma unroll
            for (int nt = 0; nt < 4; nt++) {
                short8 bf = *(const short8*)(cb + (size_t)nt * 512);
                acc[nt] = __builtin_amdgcn_mfma_f32_16x16x32_bf16(af, bf, acc[nt], 0, 0, 0);
            }
        }
#pragma unroll
        for (int nt = 0; nt < 4; nt++)
#pragma unroll
            for (int r = 0; r < 4; r++)
                atomicAdd(&upd[(rbase + r) * 68 + nt * 16 + cb16], acc[nt][r]);
    }
    __syncthreads();

    // ---- phase 2: LN1 (wave 0) -> z ----
    if (wv == 0) {
        float v[64];
        float s1 = 0.0f;
#pragma unroll
        for (int c = 0; c < 64; c++) { v[c] = z[lane * 68 + c] + upd[lane * 68 + c]; s1 += v[c]; }
        float mn = s1 * (1.0f / 64.0f);
        float s2 = 0.0f;
#pragma unroll
        for (int c = 0; c < 64; c++) { float d = v[c] - mn; s2 += d * d; }
        float rstd = 1.0f / sqrtf(s2 * (1.0f / 64.0f) + 1e-5f);
#pragma unroll
        for (int c = 0; c < 64; c++)
            z[lane * 68 + c] = (v[c] - mn) * rstd * g1s[c] + b1s[c];
    }
    __syncthreads();

    // ---- phase 3: ff = gelu(LN1 @ W1^T + b1) ----
    {
        int nq = wv >> 2;
        f32x4 acc[4] = {{0,0,0,0},{0,0,0,0},{0,0,0,0},{0,0,0,0}};
#pragma unroll
        for (int kc = 0; kc < 2; kc++) {
            f32x4 za = *(const f32x4*)&z[m * 68 + kc * 32 + kj0];
            f32x4 zb = *(const f32x4*)&z[m * 68 + kc * 32 + kj0 + 4];
            short8 af;
            af[0] = bf16r(za[0]); af[1] = bf16r(za[1]); af[2] = bf16r(za[2]); af[3] = bf16r(za[3]);
            af[4] = bf16r(zb[0]); af[5] = bf16r(zb[1]); af[6] = bf16r(zb[2]); af[7] = bf16r(zb[3]);
#pragma unroll
            for (int t = 0; t < 4; t++) {
                int nt = nq * 4 + t;
                short8 bf = *(const short8*)(w1p + ((size_t)(kc * 8 + nt) * 64 + lane) * 8);
                acc[t] = __builtin_amdgcn_mfma_f32_16x16x32_bf16(af, bf, acc[t], 0, 0, 0);
            }
        }
#pragma unroll
        for (int t = 0; t < 4; t++) {
            int col = (nq * 4 + t) * 16 + cb16;
#pragma unroll
            for (int r = 0; r < 4; r++) {
                float v = acc[t][r] + bfs1[col];
                ff[(rbase + r) * 132 + col] = 0.5f * v * (1.0f + erff(v * 0.70710678118654752f));
            }
        }
    }
    __syncthreads();

    // ---- phase 5: upd = ff @ W2^T + b2 ----
    {
        int nh = wv >> 2;
        f32x4 acc[2] = {{0,0,0,0},{0,0,0,0}};
        const float* frow = &ff[m * 132];
#pragma unroll
        for (int kc = 0; kc < 4; kc++) {
            f32x4 fa = *(const f32x4*)&frow[kc * 32 + kj0];
            f32x4 fb = *(const f32x4*)&frow[kc * 32 + kj0 + 4];
            short8 af;
            af[0] = bf16r(fa[0]); af[1] = bf16r(fa[1]); af[2] = bf16r(fa[2]); af[3] = bf16r(fa[3]);
            af[4] = bf16r(fb[0]); af[5] = bf16r(fb[1]); af[6] = bf16r(fb[2]); af[7] = bf16r(fb[3]);
#pragma unroll
            for (int t = 0; t < 2; t++) {
                int nt = nh * 2 + t;
                short8 bf = *(const short8*)(w2p + ((size_t)(kc * 4 + nt) * 64 + lane) * 8);
                acc[t] = __builtin_amdgcn_mfma_f32_16x16x32_bf16(af, bf, acc[t], 0, 0, 0);
            }
        }
#pragma unroll
        for (int t = 0; t < 2; t++) {
            int col = (nh * 2 + t) * 16 + cb16;
#pragma unroll
            for (int r = 0; r < 4; r++)
                upd[(rbase + r) * 68 + col] = acc[t][r] + bfs2[col];
        }
    }
    __syncthreads();

    // ---- phase 6: LN2 + write (wave 0) ----
    if (wv == 0) {
        float v[64];
        float s1 = 0.0f;
#pragma unroll
        for (int c = 0; c < 64; c++) { v[c] = z[lane * 68 + c] + upd[lane * 68 + c]; s1 += v[c]; }
        float mn = s1 * (1.0f / 64.0f);
        float s2 = 0.0f;
#pragma unroll
        for (int c = 0; c < 64; c++) { float d = v[c] - mn; s2 += d * d; }
        float rstd = 1.0f / sqrtf(s2 * (1.0f / 64.0f) + 1e-5f);
        int row = row0 + lane;
#pragma unroll
        for (int c = 0; c < 64; c++) {
            float res = (v[c] - mn) * rstd * g2s[c] + b2s[c];
            if (!final_layer) {
                hbuf[(size_t)row * H + c] = res;
            } else {
                out[(size_t)row * H + c] = res;
                if (row % SEQ == SEQ - 1)
                    out[(size_t)NROW * H + (row / SEQ) * H + c] = res;
            }
        }
    }
}

extern "C" void kernel_launch(void* const* d_in, const int* in_sizes, int n_in,
                              void* d_out, int out_size, void* d_ws, size_t ws_size,
                              hipStream_t stream) {
    const float* x    = (const float*)d_in[0];
    const float* wih0 = (const float*)d_in[1];
    const float* whh0 = (const float*)d_in[2];
    const float* bih0 = (const float*)d_in[3];
    const float* bhh0 = (const float*)d_in[4];
    const float* wih1 = (const float*)d_in[5];
    const float* whh1 = (const float*)d_in[6];
    const float* bih1 = (const float*)d_in[7];
    const float* bhh1 = (const float*)d_in[8];
    const float* coeffs = (const float*)d_in[9];
    const float* ln1g = (const float*)d_in[10];
    const float* ln1b = (const float*)d_in[11];
    const float* w1   = (const float*)d_in[12];
    const float* b1   = (const float*)d_in[13];
    const float* w2   = (const float*)d_in[14];
    const float* b2   = (const float*)d_in[15];
    const float* ln2g = (const float*)d_in[16];
    const float* ln2b = (const float*)d_in[17];

    float* out = (float*)d_out;
    float* ws  = (float*)d_ws;
    float* xpT = ws;                               // 16000*192 = 3,072,000 floats
    float* wtp = ws + (size_t)NROW * GDIM;         // 24,576 floats
    short* bfa = (short*)(wtp + GDIM * DM);        // bf16 fragment area
    short* cpk[2] = { bfa, bfa + 139264 };
    short* w1pk[2] = { bfa + 2 * 139264, bfa + 2 * 139264 + 8192 };
    short* w2pk[2] = { bfa + 2 * 139264 + 2 * 8192, bfa + 2 * 139264 + 3 * 8192 };
    float* hbuf = out;                             // reuse first 1,024,000 floats of d_out

    pack_wih0<<<(GDIM * DM + 255) / 256, 256, 0, stream>>>(wih0, wtp);
    for (int l = 0; l < 2; l++) {
        pack_coef_frag<<<139264 / 256, 256, 0, stream>>>(coeffs + (size_t)l * LIBN * H, cpk[l]);
        pack_w1_frag<<<8192 / 256, 256, 0, stream>>>(w1 + (size_t)l * FFD * H, w1pk[l]);
        pack_w2_frag<<<8192 / 256, 256, 0, stream>>>(w2 + (size_t)l * H * FFD, w2pk[l]);
    }
    xp0_gemm<<<NROW / 64, 192, 0, stream>>>(x, wtp, bih0, xpT);
    gru_fused<<<BSZ, 192, 0, stream>>>(xpT, whh0, bhh0, wih1, bih1, whh1, bhh1, hbuf);
    for (int l = 0; l < 2; l++) {
        sindy_mfma<<<NROW / 64, 512, 0, stream>>>(
            hbuf, cpk[l], w1pk[l], w2pk[l],
            ln1g + l * H, ln1b + l * H, b1 + l * FFD,
            b2 + l * H, ln2g + l * H, ln2b + l * H,
            out, l == 1);
    }
}